// Round 7
// baseline (223.036 us; speedup 1.0000x reference)
//
#include <hip/hip_runtime.h>

// YOLO-v1-style loss, exact port of the JAX reference.
// S=7, B=2, C=20, channels per cell = 30 (120 B):
//   ch 0..19 class, ch 20..24 box0 xywhc, ch 25..29 box1 xywhc.
// Loss only touches channels 10..29 (cls uses [5*B:]=10.. — reference quirk).
//
// R7: revert to R3 (best measured: 71.6-72.5 us) + non-temporal loads.
// Ceiling evidence (R3..R6): duration 72-77 us invariant across five
// structures AND invariant to HBM traffic (fully-L3-served replays run at
// the same speed) -> limited by the L2-fill/fabric path at ~2.6 TB/s for
// the irreducible 193 MB (every 64 B line contains live bytes; zero reuse).
// nt loads skip L2 allocation -- last possible lever on that path.

#define CH    30
#define EPSL  1e-6f
#define TPB   256

__device__ __forceinline__ float sgnf(float x) {
    return (x > 0.0f) ? 1.0f : ((x < 0.0f) ? -1.0f : 0.0f);
}

// 8-byte non-temporal load -> float2 (offsets are 8 B aligned: 120k+40+8s)
__device__ __forceinline__ float2 ldnt2(const float* addr) {
    const double d = __builtin_nontemporal_load((const double*)addr);
    float2 v;
    __builtin_memcpy(&v, &d, 8);
    return v;
}

__global__ __launch_bounds__(TPB) void yolo_loss_kernel(const float* __restrict__ p,
                                                        const float* __restrict__ a,
                                                        float* __restrict__ out,
                                                        long long n_cells) {
    __shared__ float wsum[TPB / 64];

    const int tid = threadIdx.x;
    const long long cell = (long long)blockIdx.x * TPB + tid;

    float lsum = 0.0f;
    if (cell < n_cells) {
        // pd[j] / ad[j] = channel (10+j) of this cell, j in [0,20)
        const float* cpb = p + cell * CH + 10;
        const float* cab = a + cell * CH + 10;
        float pd[20], ad[20];
#pragma unroll
        for (int i = 0; i < 10; ++i) {
            const float2 v = ldnt2(cpb + 2 * i);
            pd[2 * i] = v.x; pd[2 * i + 1] = v.y;
        }
#pragma unroll
        for (int i = 0; i < 10; ++i) {
            const float2 v = ldnt2(cab + 2 * i);
            ad[2 * i] = v.x; ad[2 * i + 1] = v.y;
        }

        // box attrs: channel 20+5b+i -> index 10+5b+i
        float pxv[2], pyv[2], pwv[2], phv[2], pcv[2];
        float axv[2], ayv[2], awv[2], ahv[2];
#pragma unroll
        for (int b = 0; b < 2; ++b) {
            pxv[b] = pd[10 + 5 * b]; pyv[b] = pd[11 + 5 * b];
            pwv[b] = pd[12 + 5 * b]; phv[b] = pd[13 + 5 * b];
            pcv[b] = pd[14 + 5 * b];
            axv[b] = ad[10 + 5 * b]; ayv[b] = ad[11 + 5 * b];
            awv[b] = ad[12 + 5 * b]; ahv[b] = ad[13 + 5 * b];
        }
        const bool obj = ad[14] > 0.0f;   // a's box-0 conf (channel 24)

        // ---- pairwise IoU, max over target boxes ----
        float miou[2];
#pragma unroll
        for (int pb = 0; pb < 2; ++pb) {
            const float p_tlx = pxv[pb] - 0.5f * pwv[pb];
            const float p_tly = pyv[pb] - 0.5f * phv[pb];
            const float p_brx = pxv[pb] + 0.5f * pwv[pb];
            const float p_bry = pyv[pb] + 0.5f * phv[pb];
            const float p_area = pwv[pb] * phv[pb];
            float best = -3.4e38f;
#pragma unroll
            for (int ab = 0; ab < 2; ++ab) {
                const float a_tlx = axv[ab] - 0.5f * awv[ab];
                const float a_tly = ayv[ab] - 0.5f * ahv[ab];
                const float a_brx = axv[ab] + 0.5f * awv[ab];
                const float a_bry = ayv[ab] + 0.5f * ahv[ab];
                float sx = fminf(p_brx, a_brx) - fmaxf(p_tlx, a_tlx);
                float sy = fminf(p_bry, a_bry) - fmaxf(p_tly, a_tly);
                sx = fmaxf(sx, 0.0f);
                sy = fmaxf(sy, 0.0f);
                const float inter = sx * sy;
                const float uni = p_area + awv[ab] * ahv[ab] - inter;
                const float iou = (uni == 0.0f) ? 0.0f : (inter / uni);  // where(zero,0)/where(zero,eps)
                best = fmaxf(best, iou);
            }
            miou[pb] = best;
        }
        // argmax over pred boxes, first-max tie-break (jnp.argmax semantics)
        const int resp = (miou[1] > miou[0]) ? 1 : 0;

        // ---- coordinate / confidence losses ----
#pragma unroll
        for (int b = 0; b < 2; ++b) {
            const bool oij = obj && (b == resp);
            if (oij) {
                const float dx = axv[b] - pxv[b];
                const float dy = ayv[b] - pyv[b];
                const float dw = sgnf(awv[b]) * sqrtf(awv[b] + EPSL) - sgnf(pwv[b]) * sqrtf(pwv[b] + EPSL);
                const float dh = sgnf(ahv[b]) * sqrtf(ahv[b] + EPSL) - sgnf(phv[b]) * sqrtf(phv[b] + EPSL);
                const float dc = 1.0f - pcv[b];  // (obj_ij^2 - obj_ij*pc)^2 with obj_ij==1
                lsum += 5.0f * (dx * dx + dy * dy + dw * dw + dh * dh) + dc * dc;
            } else {
                // noobj term: (noobj_ij*obj_ij - noobj_ij*pc)^2 = pc^2 when obj_ij==0
                lsum += 0.5f * pcv[b] * pcv[b];
            }
        }

        // ---- "class" loss over channels 10..29 (indices 0..19), gated by obj_i ----
        if (obj) {
#pragma unroll
            for (int k = 0; k < 20; ++k) {
                const float d = pd[k] - ad[k];
                lsum += d * d;
            }
        }
    }

    // ---- reduction: wave shfl -> LDS -> one atomic per block ----
    float v = lsum;
#pragma unroll
    for (int off = 32; off > 0; off >>= 1)
        v += __shfl_down(v, off, 64);
    if ((tid & 63) == 0) wsum[tid >> 6] = v;
    __syncthreads();
    if (tid == 0) {
        float t = 0.0f;
#pragma unroll
        for (int w = 0; w < TPB / 64; ++w) t += wsum[w];
        atomicAdd(out, t);
    }
}

extern "C" void kernel_launch(void* const* d_in, const int* in_sizes, int n_in,
                              void* d_out, int out_size, void* d_ws, size_t ws_size,
                              hipStream_t stream) {
    const float* p = (const float*)d_in[0];
    const float* a = (const float*)d_in[1];
    float* out = (float*)d_out;

    const long long n_cells = (long long)in_sizes[0] / CH;   // 16384*7*7 = 802816
    const int grid = (int)((n_cells + TPB - 1) / TPB);       // 3136, exact

    // d_out is re-poisoned (0xAA) before every timed replay -> must zero it here.
    hipMemsetAsync(d_out, 0, sizeof(float), stream);
    yolo_loss_kernel<<<grid, TPB, 0, stream>>>(p, a, out, n_cells);
}

// Round 8
// 204.098 us; speedup vs baseline: 1.0928x; 1.0928x over previous
//
#include <hip/hip_runtime.h>

// YOLO-v1-style loss, exact port of the JAX reference.
// S=7, B=2, C=20, channels per cell = 30 (120 B):
//   ch 0..19 class, ch 20..24 box0 xywhc, ch 25..29 box1 xywhc.
// Loss only touches channels 10..29 (cls uses [5*B:]=10.. — reference quirk).
//
// R8 = R3 verbatim (best scored config: bench 203.8 us, kernel ~72 us).
// Ceiling evidence (R1-R7): kernel duration ~71-77 us invariant across six
// structures (staged float4 / global_load_lds DMA / direct float2 / coalesced
// +LDS-transpose / pipelined persistent / barrier-free), invariant to
// occupancy 15->58%, invariant to HBM-vs-L3 sourcing (0-fetch replays run at
// identical speed), invariant to a +55% HBM-traffic change (R7 nt probe).
// Binding resource: per-CU line-fill concurrency (L1 MSHRs x fill latency).
// 3.01M irreducible 64B lines (every line contains live bytes, zero reuse)
// at the demonstrated max ~42 lines/us/CU = 2.72 TB/s chip-wide, ~86% of the
// unidirectional read rate implied by the m13 copy ubench (3.15 TB/s).
// R7's nt loads gained ~1 us kernel but cost ~20 us on the harness restore
// (L3 left cold) -> reverted.

#define CH    30
#define EPSL  1e-6f
#define TPB   256

__device__ __forceinline__ float sgnf(float x) {
    return (x > 0.0f) ? 1.0f : ((x < 0.0f) ? -1.0f : 0.0f);
}

__global__ __launch_bounds__(TPB) void yolo_loss_kernel(const float* __restrict__ p,
                                                        const float* __restrict__ a,
                                                        float* __restrict__ out,
                                                        long long n_cells) {
    __shared__ float wsum[TPB / 64];

    const int tid = threadIdx.x;
    const long long cell = (long long)blockIdx.x * TPB + tid;

    float lsum = 0.0f;
    if (cell < n_cells) {
        // pd[j] / ad[j] = channel (10+j) of this cell, j in [0,20)
        const float2* cp2 = (const float2*)(p + cell * CH + 10);
        const float2* ca2 = (const float2*)(a + cell * CH + 10);
        float pd[20], ad[20];
#pragma unroll
        for (int i = 0; i < 10; ++i) {
            const float2 v = cp2[i];
            pd[2 * i] = v.x; pd[2 * i + 1] = v.y;
        }
#pragma unroll
        for (int i = 0; i < 10; ++i) {
            const float2 v = ca2[i];
            ad[2 * i] = v.x; ad[2 * i + 1] = v.y;
        }

        // box attrs: channel 20+5b+i -> index 10+5b+i
        float pxv[2], pyv[2], pwv[2], phv[2], pcv[2];
        float axv[2], ayv[2], awv[2], ahv[2];
#pragma unroll
        for (int b = 0; b < 2; ++b) {
            pxv[b] = pd[10 + 5 * b]; pyv[b] = pd[11 + 5 * b];
            pwv[b] = pd[12 + 5 * b]; phv[b] = pd[13 + 5 * b];
            pcv[b] = pd[14 + 5 * b];
            axv[b] = ad[10 + 5 * b]; ayv[b] = ad[11 + 5 * b];
            awv[b] = ad[12 + 5 * b]; ahv[b] = ad[13 + 5 * b];
        }
        const bool obj = ad[14] > 0.0f;   // a's box-0 conf (channel 24)

        // ---- pairwise IoU, max over target boxes ----
        float miou[2];
#pragma unroll
        for (int pb = 0; pb < 2; ++pb) {
            const float p_tlx = pxv[pb] - 0.5f * pwv[pb];
            const float p_tly = pyv[pb] - 0.5f * phv[pb];
            const float p_brx = pxv[pb] + 0.5f * pwv[pb];
            const float p_bry = pyv[pb] + 0.5f * phv[pb];
            const float p_area = pwv[pb] * phv[pb];
            float best = -3.4e38f;
#pragma unroll
            for (int ab = 0; ab < 2; ++ab) {
                const float a_tlx = axv[ab] - 0.5f * awv[ab];
                const float a_tly = ayv[ab] - 0.5f * ahv[ab];
                const float a_brx = axv[ab] + 0.5f * awv[ab];
                const float a_bry = ayv[ab] + 0.5f * ahv[ab];
                float sx = fminf(p_brx, a_brx) - fmaxf(p_tlx, a_tlx);
                float sy = fminf(p_bry, a_bry) - fmaxf(p_tly, a_tly);
                sx = fmaxf(sx, 0.0f);
                sy = fmaxf(sy, 0.0f);
                const float inter = sx * sy;
                const float uni = p_area + awv[ab] * ahv[ab] - inter;
                const float iou = (uni == 0.0f) ? 0.0f : (inter / uni);  // where(zero,0)/where(zero,eps)
                best = fmaxf(best, iou);
            }
            miou[pb] = best;
        }
        // argmax over pred boxes, first-max tie-break (jnp.argmax semantics)
        const int resp = (miou[1] > miou[0]) ? 1 : 0;

        // ---- coordinate / confidence losses ----
#pragma unroll
        for (int b = 0; b < 2; ++b) {
            const bool oij = obj && (b == resp);
            if (oij) {
                const float dx = axv[b] - pxv[b];
                const float dy = ayv[b] - pyv[b];
                const float dw = sgnf(awv[b]) * sqrtf(awv[b] + EPSL) - sgnf(pwv[b]) * sqrtf(pwv[b] + EPSL);
                const float dh = sgnf(ahv[b]) * sqrtf(ahv[b] + EPSL) - sgnf(phv[b]) * sqrtf(phv[b] + EPSL);
                const float dc = 1.0f - pcv[b];  // (obj_ij^2 - obj_ij*pc)^2 with obj_ij==1
                lsum += 5.0f * (dx * dx + dy * dy + dw * dw + dh * dh) + dc * dc;
            } else {
                // noobj term: (noobj_ij*obj_ij - noobj_ij*pc)^2 = pc^2 when obj_ij==0
                lsum += 0.5f * pcv[b] * pcv[b];
            }
        }

        // ---- "class" loss over channels 10..29 (indices 0..19), gated by obj_i ----
        if (obj) {
#pragma unroll
            for (int k = 0; k < 20; ++k) {
                const float d = pd[k] - ad[k];
                lsum += d * d;
            }
        }
    }

    // ---- reduction: wave shfl -> LDS -> one atomic per block ----
    float v = lsum;
#pragma unroll
    for (int off = 32; off > 0; off >>= 1)
        v += __shfl_down(v, off, 64);
    if ((tid & 63) == 0) wsum[tid >> 6] = v;
    __syncthreads();
    if (tid == 0) {
        float t = 0.0f;
#pragma unroll
        for (int w = 0; w < TPB / 64; ++w) t += wsum[w];
        atomicAdd(out, t);
    }
}

extern "C" void kernel_launch(void* const* d_in, const int* in_sizes, int n_in,
                              void* d_out, int out_size, void* d_ws, size_t ws_size,
                              hipStream_t stream) {
    const float* p = (const float*)d_in[0];
    const float* a = (const float*)d_in[1];
    float* out = (float*)d_out;

    const long long n_cells = (long long)in_sizes[0] / CH;   // 16384*7*7 = 802816
    const int grid = (int)((n_cells + TPB - 1) / TPB);       // 3136, exact

    // d_out is re-poisoned (0xAA) before every timed replay -> must zero it here.
    hipMemsetAsync(d_out, 0, sizeof(float), stream);
    yolo_loss_kernel<<<grid, TPB, 0, stream>>>(p, a, out, n_cells);
}